// Round 4
// baseline (398.051 us; speedup 1.0000x reference)
//
#include <hip/hip_runtime.h>
#include <math.h>

#define HW 65536
#define C1F 1.0e-4f
#define C2F 9.0e-4f
#define HTS 36                 // padded ht row stride (floats); 36%32=4 spreads banks, 16B-aligned
#define HTF (42*HTS)           // per-field stride in ht

__device__ __constant__ float G11[11] = {
  0.0010284f, 0.0075987f, 0.0360008f, 0.1093607f, 0.2130056f,
  0.2660118f, 0.2130056f, 0.1093607f, 0.0360008f, 0.0075987f, 0.0010284f
};

// ws layout: float accum[0..4] = {abs_dc, ssim, hdiff, vdiff, cos};
//            unsigned mask count at byte 24; hist (B*192 uint) at byte 64.

__global__ __launch_bounds__(256, 4)
void ssim_tv_kernel(const float* __restrict__ dz_g, const float* __restrict__ cw_g,
                    const float* __restrict__ mk_g, float* __restrict__ accum)
{
  __shared__ __align__(16) float ht[5*HTF];   // 30240 B
  __shared__ float red[16];

  int bid = blockIdx.x;
  int tx = bid & 7; bid >>= 3;
  int ty = bid & 7; bid >>= 3;
  int plane = bid;              // b*3 + c
  int b = plane / 3;

  const float* dz = dz_g + (size_t)plane * HW;
  const float* cw = cw_g + (size_t)plane * HW;
  const float* mk = mk_g + (size_t)b * HW;

  int tid = threadIdx.x;
  float abs_sum = 0.f, h_sum = 0.f, v_sum = 0.f, ssim_sum = 0.f;

  // ---- horizontal 11-tap directly from global (L1-served), 336 runs of 4 cols ----
  for (int run = tid; run < 336; run += 256) {
    int hr = run >> 3;                 // 0..41 (ht row)
    int jr = run & 7;                  // 0..7
    int gr = ty*32 - 5 + hr;           // global row, may be OOB
    int grc = min(max(gr, 0), 255);
    float rowv = ((unsigned)gr < 256u) ? 1.f : 0.f;
    int cbase = tx*32 + 4*jr;          // output base col (0..252)
    int fi0 = (cbase >> 2) - 2;        // first float4 idx of 20-float window

    const float4* rdz = (const float4*)(dz + grc*256);
    const float4* rcw = (const float4*)(cw + grc*256);
    const float4* rmk = (const float4*)(mk + grc*256);

    float d[14], c[14];                // masked values at window idx 3..16
#pragma unroll
    for (int q = 0; q < 5; ++q) {
      int fi = fi0 + q;
      int fic = min(max(fi, 0), 63);
      float4 aq = rdz[fic];
      float4 bq = rcw[fic];
      float4 mq = rmk[fic];
      float vf = (((unsigned)fi < 64u) ? 1.f : 0.f) * rowv;
      float ae[4] = {aq.x, aq.y, aq.z, aq.w};
      float be[4] = {bq.x, bq.y, bq.z, bq.w};
      float me[4] = {mq.x*vf, mq.y*vf, mq.z*vf, mq.w*vf};
#pragma unroll
      for (int e = 0; e < 4; ++e) {
        int wi = 4*q + e;
        if (wi >= 3 && wi <= 16) { d[wi-3] = ae[e]*me[e]; c[wi-3] = be[e]*me[e]; }
      }
    }

    float m1[4] = {0,0,0,0}, m2[4] = {0,0,0,0};
    float s11[4] = {0,0,0,0}, s22[4] = {0,0,0,0}, s12[4] = {0,0,0,0};
#pragma unroll
    for (int k = 0; k < 11; ++k) {
      float w = G11[k];
#pragma unroll
      for (int j = 0; j < 4; ++j) {
        float a = d[j+k], bb = c[j+k];
        float wa = w*a, wb = w*bb;
        m1[j]  = fmaf(w, a,  m1[j]);
        m2[j]  = fmaf(w, bb, m2[j]);
        s11[j] = fmaf(wa, a,  s11[j]);
        s22[j] = fmaf(wb, bb, s22[j]);
        s12[j] = fmaf(wa, bb, s12[j]);
      }
    }
    int o = hr*HTS + 4*jr;
    *(float4*)&ht[0*HTF + o] = make_float4(m1[0],m1[1],m1[2],m1[3]);
    *(float4*)&ht[1*HTF + o] = make_float4(m2[0],m2[1],m2[2],m2[3]);
    *(float4*)&ht[2*HTF + o] = make_float4(s11[0],s11[1],s11[2],s11[3]);
    *(float4*)&ht[3*HTF + o] = make_float4(s22[0],s22[1],s22[2],s22[3]);
    *(float4*)&ht[4*HTF + o] = make_float4(s12[0],s12[1],s12[2],s12[3]);

    // fused terms on interior rows (hr in [5,36] <=> gr in tile rows, in-bounds)
    float itf = (hr >= 5 && hr <= 36) ? 1.f : 0.f;
    // L1 |d-c| on run cols (window 8..11 -> local 5..8)
    abs_sum += itf * (fabsf(d[5]-c[5]) + fabsf(d[6]-c[6])
                    + fabsf(d[7]-c[7]) + fabsf(d[8]-c[8]));
    // h-TV: |d(col)-d(col+1)|, col<255 (only cbase+3==255 can fail)
    float h3 = (cbase + 3 < 255) ? 1.f : 0.f;
    h_sum += itf * (fabsf(d[5]-d[6]) + fabsf(d[6]-d[7])
                  + fabsf(d[7]-d[8]) + h3*fabsf(d[8]-d[9]));
    // v-TV: |d(gr)-d(gr+1)| on run cols; row below via 2 extra L1-hot loads.
    // gr2 MUST be clamped on both sides: gr can be as low as -5, and an
    // unclamped gr2=-4 reads before the allocation (round-3 crash).
    {
      int gr2 = min(max(gr + 1, 0), 255);
      float4 a2 = ((const float4*)(dz + gr2*256))[fi0 + 2];
      float4 m2q = ((const float4*)(mk + gr2*256))[fi0 + 2];
      float vtf = itf * ((gr < 255) ? 1.f : 0.f);
      v_sum += vtf * (fabsf(d[5] - a2.x*m2q.x) + fabsf(d[6] - a2.y*m2q.y)
                    + fabsf(d[7] - a2.z*m2q.z) + fabsf(d[8] - a2.w*m2q.w));
    }
  }
  __syncthreads();

  // ---- vertical 11-tap, 4-row register blocking + SSIM map ----
  {
    int col = tid & 31;
    int r0 = (tid >> 5) << 2;     // 0,4,...,28
    float acc[5][4];
#pragma unroll
    for (int f = 0; f < 5; ++f)
#pragma unroll
      for (int j = 0; j < 4; ++j) acc[f][j] = 0.f;
#pragma unroll
    for (int k = 0; k < 14; ++k) {
      int o = (r0 + k)*HTS + col;
#pragma unroll
      for (int f = 0; f < 5; ++f) {
        float v = ht[f*HTF + o];
#pragma unroll
        for (int j = 0; j < 4; ++j) {
          int t = k - j;
          if (t >= 0 && t < 11)
            acc[f][j] = fmaf(G11[t], v, acc[f][j]);
        }
      }
    }
#pragma unroll
    for (int j = 0; j < 4; ++j) {
      float mu1 = acc[0][j], mu2 = acc[1][j];
      float x11 = acc[2][j], x22 = acc[3][j], x12 = acc[4][j];
      float mu1s = mu1*mu1, mu2s = mu2*mu2, mu12 = mu1*mu2;
      float num = (2.f*mu12 + C1F) * (2.f*(x12 - mu12) + C2F);
      float den = (mu1s + mu2s + C1F) * ((x11 - mu1s) + (x22 - mu2s) + C2F);
      ssim_sum += num * __builtin_amdgcn_rcpf(den);
    }
  }

#pragma unroll
  for (int off = 32; off > 0; off >>= 1) {
    abs_sum  += __shfl_down(abs_sum,  off);
    ssim_sum += __shfl_down(ssim_sum, off);
    h_sum    += __shfl_down(h_sum,    off);
    v_sum    += __shfl_down(v_sum,    off);
  }
  if ((tid & 63) == 0) {
    int w = tid >> 6;
    red[w*4+0]=abs_sum; red[w*4+1]=ssim_sum; red[w*4+2]=h_sum; red[w*4+3]=v_sum;
  }
  __syncthreads();
  if (tid < 4) {
    float s = red[tid] + red[4+tid] + red[8+tid] + red[12+tid];
    atomicAdd(&accum[tid], s);
  }
}

__device__ __forceinline__ void cos_hist_px(float mv, float g0, float g1, float g2,
                                            float P0, float P1, float P2,
                                            float& cos_sum, unsigned& cnt,
                                            unsigned* lh)
{
  // bin = floor(g*64) clipped (algebraically equals the reference index chain)
  int i0 = min(max((int)(g0*64.f), 0), 63);
  int i1 = min(max((int)(g1*64.f), 0), 63);
  int i2 = min(max((int)(g2*64.f), 0), 63);
  atomicAdd(&lh[i0],     1u);
  atomicAdd(&lh[64+i1],  1u);
  atomicAdd(&lh[128+i2], 1u);

  float p0 = P0*mv, p1 = P1*mv, p2 = P2*mv;
  float np2 = p0*p0 + p1*p1 + p2*p2;
  float invp = __builtin_amdgcn_rsqf(fmaxf(np2, 1e-24f));   // 1/max(||p||,1e-12)
  float t0 = (g0*mv*2.f - 1.f)*mv;
  float t1 = (g1*mv*2.f - 1.f)*mv;
  float t2 = (g2*mv*2.f - 1.f)*mv;
  float t2n = t0*t0 + t1*t1 + t2*t2;
  float invt = __builtin_amdgcn_rsqf(fmaxf(t2n, 1e-16f));   // 1/max(||t||,1e-8)
  float dot = p0*t0 + p1*t1 + p2*t2;
  // q = p*invp has ||q|| == 1 whenever p != 0 (n1==1); p==0 gives dot==0 -> cos=1
  cos_sum += 1.f - dot * invp * invt;
  cnt += (mv != 0.f) ? 1u : 0u;
}

__global__ __launch_bounds__(256)
void cos_hist_kernel(const float* __restrict__ pr, const float* __restrict__ gt,
                     const float* __restrict__ mk, float* __restrict__ accum,
                     unsigned* __restrict__ mcount, unsigned* __restrict__ hist)
{
  __shared__ unsigned lh[192];
  __shared__ float redf[4];
  __shared__ unsigned redi[4];
  int tid = threadIdx.x;
  for (int i = tid; i < 192; i += 256) lh[i] = 0u;
  __syncthreads();

  int b = blockIdx.x >> 5;
  int chunk = blockIdx.x & 31;          // 32 chunks of 2048 px
  const float4* pv = (const float4*)(pr + (size_t)b*3*HW);
  const float4* gv = (const float4*)(gt + (size_t)b*3*HW);
  const float4* mv4 = (const float4*)(mk + (size_t)b*HW);
  int base4 = chunk*512;

  float cos_sum = 0.f;
  unsigned cnt = 0u;
#pragma unroll
  for (int it = 0; it < 2; ++it) {
    int i4 = base4 + it*256 + tid;
    float4 M  = mv4[i4];
    float4 G0 = gv[i4], G1 = gv[16384 + i4], G2 = gv[2*16384 + i4];
    float4 P0 = pv[i4], P1 = pv[16384 + i4], P2 = pv[2*16384 + i4];
    cos_hist_px(M.x, G0.x, G1.x, G2.x, P0.x, P1.x, P2.x, cos_sum, cnt, lh);
    cos_hist_px(M.y, G0.y, G1.y, G2.y, P0.y, P1.y, P2.y, cos_sum, cnt, lh);
    cos_hist_px(M.z, G0.z, G1.z, G2.z, P0.z, P1.z, P2.z, cos_sum, cnt, lh);
    cos_hist_px(M.w, G0.w, G1.w, G2.w, P0.w, P1.w, P2.w, cos_sum, cnt, lh);
  }

#pragma unroll
  for (int off = 32; off > 0; off >>= 1) {
    cos_sum += __shfl_down(cos_sum, off);
    cnt     += __shfl_down(cnt,     off);
  }
  if ((tid & 63) == 0) { redf[tid>>6] = cos_sum; redi[tid>>6] = cnt; }
  __syncthreads();
  if (tid == 0) {
    atomicAdd(&accum[4], redf[0]+redf[1]+redf[2]+redf[3]);
    atomicAdd(mcount, redi[0]+redi[1]+redi[2]+redi[3]);
  }
  for (int i = tid; i < 192; i += 256) {
    unsigned v = lh[i];
    if (v) atomicAdd(&hist[b*192 + i], v);
  }
}

__global__ __launch_bounds__(256)
void finalize_kernel(const float* __restrict__ nh, const unsigned* __restrict__ hist,
                     const float* __restrict__ accum, const unsigned* __restrict__ mcount,
                     float* __restrict__ out, int B)
{
  __shared__ float red[4];
  int tid = threadIdx.x;
  int n = B*192;
  float hs = 0.f;
  for (int i = tid; i < n; i += 256)
    hs += fabsf(nh[i] - (float)hist[i] * (1.f/65536.f));
#pragma unroll
  for (int off = 32; off > 0; off >>= 1) hs += __shfl_down(hs, off);
  if ((tid & 63) == 0) red[tid>>6] = hs;
  __syncthreads();
  if (tid == 0) {
    float hist_sum = red[0]+red[1]+red[2]+red[3];
    float Np = (float)B * 3.f * 65536.f;
    float L_dehaze = accum[0] / Np;
    float L_ssim = 1.f - accum[1] / Np;
    float L_tv = accum[2] / ((float)B*3.f*256.f*255.f)
               + accum[3] / ((float)B*3.f*255.f*256.f);
    float L_hist = hist_sum / (float)n;
    float M = (float)(*mcount);
    float back = (float)B * 65536.f - M;
    float L_normal = (accum[4] - back) / M;
    out[0] = 10.f*L_dehaze + L_ssim + L_tv + L_hist + 100.f*L_normal;
  }
}

extern "C" void kernel_launch(void* const* d_in, const int* in_sizes, int n_in,
                              void* d_out, int out_size, void* d_ws, size_t ws_size,
                              hipStream_t stream)
{
  const float* predict = (const float*)d_in[0];
  const float* gt      = (const float*)d_in[1];
  const float* dehaze  = (const float*)d_in[2];
  const float* cleanw  = (const float*)d_in[3];
  const float* nh      = (const float*)d_in[4];
  const float* mask    = (const float*)d_in[5];
  int B = in_sizes[0] / (3*HW);

  float* accum      = (float*)d_ws;
  unsigned* mcount  = (unsigned*)((char*)d_ws + 24);
  unsigned* hist    = (unsigned*)((char*)d_ws + 64);

  hipMemsetAsync(d_ws, 0, 64 + (size_t)B*192*4, stream);

  cos_hist_kernel<<<B*32, 256, 0, stream>>>(predict, gt, mask, accum, mcount, hist);
  ssim_tv_kernel<<<B*3*64, 256, 0, stream>>>(dehaze, cleanw, mask, accum);
  finalize_kernel<<<1, 256, 0, stream>>>(nh, hist, accum, mcount, (float*)d_out, B);
}

// Round 5
// 380.013 us; speedup vs baseline: 1.0475x; 1.0475x over previous
//
#include <hip/hip_runtime.h>
#include <math.h>

#define HW 65536
#define C1F 1.0e-4f
#define C2F 9.0e-4f
#define HTS 36                 // padded ht row stride (floats); 36%32=4 spreads banks, 16B-aligned
#define HTF (42*HTS)           // per-field stride in ht

__device__ __constant__ float G11[11] = {
  0.0010284f, 0.0075987f, 0.0360008f, 0.1093607f, 0.2130056f,
  0.2660118f, 0.2130056f, 0.1093607f, 0.0360008f, 0.0075987f, 0.0010284f
};

// ws layout: float accum[0..4] = {abs_dc, ssim, hdiff, vdiff, cos};
//            unsigned mask count at byte 24; hist (B*192 uint) at byte 64.

// LDS = 30.72 KB -> 5 blocks/CU; (256,5) caps VGPR at 102 (we use ~50) so
// occupancy is LDS-limited at 20 waves/CU, not launch-bounds-limited.
__global__ __launch_bounds__(256, 5)
void ssim_tv_kernel(const float* __restrict__ dz_g, const float* __restrict__ cw_g,
                    const float* __restrict__ mk_g, float* __restrict__ accum)
{
  __shared__ __align__(16) float ht[5*HTF];   // 30240 B
  __shared__ float red[16];

  int bid = blockIdx.x;
  int tx = bid & 7; bid >>= 3;
  int ty = bid & 7; bid >>= 3;
  int plane = bid;              // b*3 + c
  int b = plane / 3;

  const float* dz = dz_g + (size_t)plane * HW;
  const float* cw = cw_g + (size_t)plane * HW;
  const float* mk = mk_g + (size_t)b * HW;

  int tid = threadIdx.x;
  float abs_sum = 0.f, h_sum = 0.f, v_sum = 0.f, ssim_sum = 0.f;

  // ---- horizontal 11-tap directly from global (L1-served), 336 runs of 4 cols ----
  for (int run = tid; run < 336; run += 256) {
    int hr = run >> 3;                 // 0..41 (ht row)
    int jr = run & 7;                  // 0..7
    int gr = ty*32 - 5 + hr;           // global row, may be OOB
    int grc = min(max(gr, 0), 255);
    float rowv = ((unsigned)gr < 256u) ? 1.f : 0.f;
    int cbase = tx*32 + 4*jr;          // output base col (0..252)
    int fi0 = (cbase >> 2) - 2;        // first float4 idx of 20-float window

    const float4* rdz = (const float4*)(dz + grc*256);
    const float4* rcw = (const float4*)(cw + grc*256);
    const float4* rmk = (const float4*)(mk + grc*256);

    // ---- issue ALL global loads up front (incl. v-TV row-below) ----
    float4 aq[5], bq[5], mq[5];
#pragma unroll
    for (int q = 0; q < 5; ++q) {
      int fi = fi0 + q;
      int fic = min(max(fi, 0), 63);
      aq[q] = rdz[fic];
      bq[q] = rcw[fic];
      mq[q] = rmk[fic];
    }
    // v-TV row below: clamp BOTH sides (gr can be -5; round-3 crash)
    int gr2 = min(max(gr + 1, 0), 255);
    float4 a2  = ((const float4*)(dz + gr2*256))[fi0 + 2];
    float4 m2q = ((const float4*)(mk + gr2*256))[fi0 + 2];

    float d[14], c[14];                // masked values at window idx 3..16
#pragma unroll
    for (int q = 0; q < 5; ++q) {
      int fi = fi0 + q;
      float vf = (((unsigned)fi < 64u) ? 1.f : 0.f) * rowv;
      float ae[4] = {aq[q].x, aq[q].y, aq[q].z, aq[q].w};
      float be[4] = {bq[q].x, bq[q].y, bq[q].z, bq[q].w};
      float me[4] = {mq[q].x*vf, mq[q].y*vf, mq[q].z*vf, mq[q].w*vf};
#pragma unroll
      for (int e = 0; e < 4; ++e) {
        int wi = 4*q + e;
        if (wi >= 3 && wi <= 16) { d[wi-3] = ae[e]*me[e]; c[wi-3] = be[e]*me[e]; }
      }
    }

    float m1[4] = {0,0,0,0}, m2[4] = {0,0,0,0};
    float s11[4] = {0,0,0,0}, s22[4] = {0,0,0,0}, s12[4] = {0,0,0,0};
#pragma unroll
    for (int k = 0; k < 11; ++k) {
      float w = G11[k];
#pragma unroll
      for (int j = 0; j < 4; ++j) {
        float a = d[j+k], bb = c[j+k];
        float wa = w*a, wb = w*bb;
        m1[j]  = fmaf(w, a,  m1[j]);
        m2[j]  = fmaf(w, bb, m2[j]);
        s11[j] = fmaf(wa, a,  s11[j]);
        s22[j] = fmaf(wb, bb, s22[j]);
        s12[j] = fmaf(wa, bb, s12[j]);
      }
    }
    int o = hr*HTS + 4*jr;
    *(float4*)&ht[0*HTF + o] = make_float4(m1[0],m1[1],m1[2],m1[3]);
    *(float4*)&ht[1*HTF + o] = make_float4(m2[0],m2[1],m2[2],m2[3]);
    *(float4*)&ht[2*HTF + o] = make_float4(s11[0],s11[1],s11[2],s11[3]);
    *(float4*)&ht[3*HTF + o] = make_float4(s22[0],s22[1],s22[2],s22[3]);
    *(float4*)&ht[4*HTF + o] = make_float4(s12[0],s12[1],s12[2],s12[3]);

    // fused terms on interior rows (hr in [5,36] <=> gr in tile rows, in-bounds)
    float itf = (hr >= 5 && hr <= 36) ? 1.f : 0.f;
    // L1 |d-c| on run cols (window 8..11 -> local 5..8)
    abs_sum += itf * (fabsf(d[5]-c[5]) + fabsf(d[6]-c[6])
                    + fabsf(d[7]-c[7]) + fabsf(d[8]-c[8]));
    // h-TV: |d(col)-d(col+1)|, col<255 (only cbase+3==255 can fail)
    float h3 = (cbase + 3 < 255) ? 1.f : 0.f;
    h_sum += itf * (fabsf(d[5]-d[6]) + fabsf(d[6]-d[7])
                  + fabsf(d[7]-d[8]) + h3*fabsf(d[8]-d[9]));
    // v-TV: |d(gr)-d(gr+1)| on run cols
    {
      float vtf = itf * ((gr < 255) ? 1.f : 0.f);
      v_sum += vtf * (fabsf(d[5] - a2.x*m2q.x) + fabsf(d[6] - a2.y*m2q.y)
                    + fabsf(d[7] - a2.z*m2q.z) + fabsf(d[8] - a2.w*m2q.w));
    }
  }
  __syncthreads();

  // ---- vertical 11-tap, 4-row register blocking + SSIM map ----
  {
    int col = tid & 31;
    int r0 = (tid >> 5) << 2;     // 0,4,...,28
    float acc[5][4];
#pragma unroll
    for (int f = 0; f < 5; ++f)
#pragma unroll
      for (int j = 0; j < 4; ++j) acc[f][j] = 0.f;
#pragma unroll
    for (int k = 0; k < 14; ++k) {
      int o = (r0 + k)*HTS + col;
#pragma unroll
      for (int f = 0; f < 5; ++f) {
        float v = ht[f*HTF + o];
#pragma unroll
        for (int j = 0; j < 4; ++j) {
          int t = k - j;
          if (t >= 0 && t < 11)
            acc[f][j] = fmaf(G11[t], v, acc[f][j]);
        }
      }
    }
#pragma unroll
    for (int j = 0; j < 4; ++j) {
      float mu1 = acc[0][j], mu2 = acc[1][j];
      float x11 = acc[2][j], x22 = acc[3][j], x12 = acc[4][j];
      float mu1s = mu1*mu1, mu2s = mu2*mu2, mu12 = mu1*mu2;
      float num = (2.f*mu12 + C1F) * (2.f*(x12 - mu12) + C2F);
      float den = (mu1s + mu2s + C1F) * ((x11 - mu1s) + (x22 - mu2s) + C2F);
      ssim_sum += num * __builtin_amdgcn_rcpf(den);
    }
  }

#pragma unroll
  for (int off = 32; off > 0; off >>= 1) {
    abs_sum  += __shfl_down(abs_sum,  off);
    ssim_sum += __shfl_down(ssim_sum, off);
    h_sum    += __shfl_down(h_sum,    off);
    v_sum    += __shfl_down(v_sum,    off);
  }
  if ((tid & 63) == 0) {
    int w = tid >> 6;
    red[w*4+0]=abs_sum; red[w*4+1]=ssim_sum; red[w*4+2]=h_sum; red[w*4+3]=v_sum;
  }
  __syncthreads();
  if (tid < 4) {
    float s = red[tid] + red[4+tid] + red[8+tid] + red[12+tid];
    atomicAdd(&accum[tid], s);
  }
}

__device__ __forceinline__ void cos_hist_px(float mv, float g0, float g1, float g2,
                                            float P0, float P1, float P2,
                                            float& cos_sum, unsigned& cnt,
                                            unsigned* lh)
{
  // bin = floor(g*64) clipped (algebraically equals the reference index chain)
  int i0 = min(max((int)(g0*64.f), 0), 63);
  int i1 = min(max((int)(g1*64.f), 0), 63);
  int i2 = min(max((int)(g2*64.f), 0), 63);
  atomicAdd(&lh[i0],     1u);
  atomicAdd(&lh[64+i1],  1u);
  atomicAdd(&lh[128+i2], 1u);

  float p0 = P0*mv, p1 = P1*mv, p2 = P2*mv;
  float np2 = p0*p0 + p1*p1 + p2*p2;
  float invp = __builtin_amdgcn_rsqf(fmaxf(np2, 1e-24f));   // 1/max(||p||,1e-12)
  float t0 = (g0*mv*2.f - 1.f)*mv;
  float t1 = (g1*mv*2.f - 1.f)*mv;
  float t2 = (g2*mv*2.f - 1.f)*mv;
  float t2n = t0*t0 + t1*t1 + t2*t2;
  float invt = __builtin_amdgcn_rsqf(fmaxf(t2n, 1e-16f));   // 1/max(||t||,1e-8)
  float dot = p0*t0 + p1*t1 + p2*t2;
  // q = p*invp has ||q|| == 1 whenever p != 0 (n1==1); p==0 gives dot==0 -> cos=1
  cos_sum += 1.f - dot * invp * invt;
  cnt += (mv != 0.f) ? 1u : 0u;
}

__global__ __launch_bounds__(256)
void cos_hist_kernel(const float* __restrict__ pr, const float* __restrict__ gt,
                     const float* __restrict__ mk, float* __restrict__ accum,
                     unsigned* __restrict__ mcount, unsigned* __restrict__ hist)
{
  __shared__ unsigned lh[192];
  __shared__ float redf[4];
  __shared__ unsigned redi[4];
  int tid = threadIdx.x;
  for (int i = tid; i < 192; i += 256) lh[i] = 0u;
  __syncthreads();

  // B*8 blocks: 8192 px (2048 float4s) per block -> 4x fewer global hist
  // atomics and 4x fewer same-line accum atomics than B*32.
  int b = blockIdx.x >> 3;
  int chunk = blockIdx.x & 7;
  const float4* pv = (const float4*)(pr + (size_t)b*3*HW);
  const float4* gv = (const float4*)(gt + (size_t)b*3*HW);
  const float4* mv4 = (const float4*)(mk + (size_t)b*HW);
  int base4 = chunk*2048;

  float cos_sum = 0.f;
  unsigned cnt = 0u;
  for (int it = 0; it < 8; ++it) {
    int i4 = base4 + it*256 + tid;
    float4 M  = mv4[i4];
    float4 G0 = gv[i4], G1 = gv[16384 + i4], G2 = gv[2*16384 + i4];
    float4 P0 = pv[i4], P1 = pv[16384 + i4], P2 = pv[2*16384 + i4];
    cos_hist_px(M.x, G0.x, G1.x, G2.x, P0.x, P1.x, P2.x, cos_sum, cnt, lh);
    cos_hist_px(M.y, G0.y, G1.y, G2.y, P0.y, P1.y, P2.y, cos_sum, cnt, lh);
    cos_hist_px(M.z, G0.z, G1.z, G2.z, P0.z, P1.z, P2.z, cos_sum, cnt, lh);
    cos_hist_px(M.w, G0.w, G1.w, G2.w, P0.w, P1.w, P2.w, cos_sum, cnt, lh);
  }

#pragma unroll
  for (int off = 32; off > 0; off >>= 1) {
    cos_sum += __shfl_down(cos_sum, off);
    cnt     += __shfl_down(cnt,     off);
  }
  if ((tid & 63) == 0) { redf[tid>>6] = cos_sum; redi[tid>>6] = cnt; }
  __syncthreads();
  if (tid == 0) {
    atomicAdd(&accum[4], redf[0]+redf[1]+redf[2]+redf[3]);
    atomicAdd(mcount, redi[0]+redi[1]+redi[2]+redi[3]);
  }
  for (int i = tid; i < 192; i += 256) {
    unsigned v = lh[i];
    if (v) atomicAdd(&hist[b*192 + i], v);
  }
}

__global__ __launch_bounds__(256)
void finalize_kernel(const float* __restrict__ nh, const unsigned* __restrict__ hist,
                     const float* __restrict__ accum, const unsigned* __restrict__ mcount,
                     float* __restrict__ out, int B)
{
  __shared__ float red[4];
  int tid = threadIdx.x;
  int n = B*192;
  float hs = 0.f;
  for (int i = tid; i < n; i += 256)
    hs += fabsf(nh[i] - (float)hist[i] * (1.f/65536.f));
#pragma unroll
  for (int off = 32; off > 0; off >>= 1) hs += __shfl_down(hs, off);
  if ((tid & 63) == 0) red[tid>>6] = hs;
  __syncthreads();
  if (tid == 0) {
    float hist_sum = red[0]+red[1]+red[2]+red[3];
    float Np = (float)B * 3.f * 65536.f;
    float L_dehaze = accum[0] / Np;
    float L_ssim = 1.f - accum[1] / Np;
    float L_tv = accum[2] / ((float)B*3.f*256.f*255.f)
               + accum[3] / ((float)B*3.f*255.f*256.f);
    float L_hist = hist_sum / (float)n;
    float M = (float)(*mcount);
    float back = (float)B * 65536.f - M;
    float L_normal = (accum[4] - back) / M;
    out[0] = 10.f*L_dehaze + L_ssim + L_tv + L_hist + 100.f*L_normal;
  }
}

extern "C" void kernel_launch(void* const* d_in, const int* in_sizes, int n_in,
                              void* d_out, int out_size, void* d_ws, size_t ws_size,
                              hipStream_t stream)
{
  const float* predict = (const float*)d_in[0];
  const float* gt      = (const float*)d_in[1];
  const float* dehaze  = (const float*)d_in[2];
  const float* cleanw  = (const float*)d_in[3];
  const float* nh      = (const float*)d_in[4];
  const float* mask    = (const float*)d_in[5];
  int B = in_sizes[0] / (3*HW);

  float* accum      = (float*)d_ws;
  unsigned* mcount  = (unsigned*)((char*)d_ws + 24);
  unsigned* hist    = (unsigned*)((char*)d_ws + 64);

  hipMemsetAsync(d_ws, 0, 64 + (size_t)B*192*4, stream);

  cos_hist_kernel<<<B*8, 256, 0, stream>>>(predict, gt, mask, accum, mcount, hist);
  ssim_tv_kernel<<<B*3*64, 256, 0, stream>>>(dehaze, cleanw, mask, accum);
  finalize_kernel<<<1, 256, 0, stream>>>(nh, hist, accum, mcount, (float*)d_out, B);
}

// Round 6
// 374.644 us; speedup vs baseline: 1.0625x; 1.0143x over previous
//
#include <hip/hip_runtime.h>
#include <math.h>

#define HW 65536
#define C1F 1.0e-4f
#define C2F 9.0e-4f
#define STE 34                 // htE/htQ row stride in v2f (272B: rows advance 4 banks)
#define STP 36                 // htP row stride in floats (144B, matched R4's 0-conflict layout)

typedef float v2f __attribute__((ext_vector_type(2)));

__device__ __constant__ float G11[11] = {
  0.0010284f, 0.0075987f, 0.0360008f, 0.1093607f, 0.2130056f,
  0.2660118f, 0.2130056f, 0.1093607f, 0.0360008f, 0.0075987f, 0.0010284f
};

// ws layout: float accum[0..4] = {abs_dc, ssim, hdiff, vdiff, cos};
//            unsigned mask count at byte 24; hist (B*192 uint) at byte 64.

__global__ __launch_bounds__(256, 4)
void ssim_tv_kernel(const float* __restrict__ dz_g, const float* __restrict__ cw_g,
                    const float* __restrict__ mk_g, float* __restrict__ accum)
{
  // Field-interleaved horizontal-conv results:
  //   htE[i] = {mu1_h, mu2_h}, htQ[i] = {s11_h, s22_h}, htP[i] = s12_h
  __shared__ __align__(16) v2f  htE[42*STE];   // 11424 B
  __shared__ __align__(16) v2f  htQ[42*STE];   // 11424 B
  __shared__ __align__(16) float htP[42*STP];  //  6048 B
  __shared__ float red[16];

  int bid = blockIdx.x;
  int tx = bid & 7; bid >>= 3;
  int ty = bid & 7; bid >>= 3;
  int plane = bid;              // b*3 + c
  int b = plane / 3;

  const float* dz = dz_g + (size_t)plane * HW;
  const float* cw = cw_g + (size_t)plane * HW;
  const float* mk = mk_g + (size_t)b * HW;

  int tid = threadIdx.x;
  float abs_sum = 0.f, h_sum = 0.f, v_sum = 0.f, ssim_sum = 0.f;

  // ---- horizontal 11-tap directly from global (L1-served), 336 runs of 4 cols ----
  for (int run = tid; run < 336; run += 256) {
    int hr = run >> 3;                 // 0..41 (ht row)
    int jr = run & 7;                  // 0..7
    int gr = ty*32 - 5 + hr;           // global row, may be OOB
    int grc = min(max(gr, 0), 255);
    float rowv = ((unsigned)gr < 256u) ? 1.f : 0.f;
    int cbase = tx*32 + 4*jr;          // output base col (0..252)
    int fi0 = (cbase >> 2) - 2;        // first float4 idx of 20-float window

    const float4* rdz = (const float4*)(dz + grc*256);
    const float4* rcw = (const float4*)(cw + grc*256);
    const float4* rmk = (const float4*)(mk + grc*256);

    v2f e2[14];                        // {d, c} masked, window idx 3..16
#pragma unroll
    for (int q = 0; q < 5; ++q) {
      int fi = fi0 + q;
      int fic = min(max(fi, 0), 63);
      float4 aq = rdz[fic];
      float4 bq = rcw[fic];
      float4 mq = rmk[fic];
      float vf = (((unsigned)fi < 64u) ? 1.f : 0.f) * rowv;
      float ae[4] = {aq.x, aq.y, aq.z, aq.w};
      float be[4] = {bq.x, bq.y, bq.z, bq.w};
      float me[4] = {mq.x*vf, mq.y*vf, mq.z*vf, mq.w*vf};
#pragma unroll
      for (int e = 0; e < 4; ++e) {
        int wi = 4*q + e;
        if (wi >= 3 && wi <= 16) {
          v2f t; t.x = ae[e]*me[e]; t.y = be[e]*me[e];
          e2[wi-3] = t;
        }
      }
    }

    // products hoisted out of the tap loop
    v2f q2[14]; float dp[14];
#pragma unroll
    for (int i = 0; i < 14; ++i) {
      q2[i] = e2[i]*e2[i];             // {d*d, c*c} (v_pk_mul_f32)
      dp[i] = e2[i].x * e2[i].y;       // d*c
    }

    v2f aE[4] = {{0,0},{0,0},{0,0},{0,0}};   // {mu1, mu2}
    v2f aQ[4] = {{0,0},{0,0},{0,0},{0,0}};   // {s11, s22}
    float aP[4] = {0,0,0,0};                 // s12
#pragma unroll
    for (int k = 0; k < 11; ++k) {
      float w = G11[k];
#pragma unroll
      for (int j = 0; j < 4; ++j) {
        aE[j] += w * e2[j+k];          // 1 v_pk_fma_f32
        aQ[j] += w * q2[j+k];          // 1 v_pk_fma_f32
        aP[j] = fmaf(w, dp[j+k], aP[j]);
      }
    }
    int o = hr*STE + 4*jr;             // even -> 16B aligned
    *(float4*)&htE[o]   = make_float4(aE[0].x, aE[0].y, aE[1].x, aE[1].y);
    *(float4*)&htE[o+2] = make_float4(aE[2].x, aE[2].y, aE[3].x, aE[3].y);
    *(float4*)&htQ[o]   = make_float4(aQ[0].x, aQ[0].y, aQ[1].x, aQ[1].y);
    *(float4*)&htQ[o+2] = make_float4(aQ[2].x, aQ[2].y, aQ[3].x, aQ[3].y);
    *(float4*)&htP[hr*STP + 4*jr] = make_float4(aP[0], aP[1], aP[2], aP[3]);

    // fused terms on interior rows (hr in [5,36] <=> gr in tile rows, in-bounds)
    float itf = (hr >= 5 && hr <= 36) ? 1.f : 0.f;
    // L1 |d-c| on run cols (window 8..11 -> local 5..8)
    abs_sum += itf * (fabsf(e2[5].x-e2[5].y) + fabsf(e2[6].x-e2[6].y)
                    + fabsf(e2[7].x-e2[7].y) + fabsf(e2[8].x-e2[8].y));
    // h-TV: |d(col)-d(col+1)|, col<255 (only cbase+3==255 can fail)
    float h3 = (cbase + 3 < 255) ? 1.f : 0.f;
    h_sum += itf * (fabsf(e2[5].x-e2[6].x) + fabsf(e2[6].x-e2[7].x)
                  + fabsf(e2[7].x-e2[8].x) + h3*fabsf(e2[8].x-e2[9].x));
    // v-TV: |d(gr)-d(gr+1)|; gr2 clamped BOTH sides (gr can be -5; round-3 crash)
    {
      int gr2 = min(max(gr + 1, 0), 255);
      float4 a2  = ((const float4*)(dz + gr2*256))[fi0 + 2];
      float4 m2q = ((const float4*)(mk + gr2*256))[fi0 + 2];
      float vtf = itf * ((gr < 255) ? 1.f : 0.f);
      v_sum += vtf * (fabsf(e2[5].x - a2.x*m2q.x) + fabsf(e2[6].x - a2.y*m2q.y)
                    + fabsf(e2[7].x - a2.z*m2q.z) + fabsf(e2[8].x - a2.w*m2q.w));
    }
  }
  __syncthreads();

  // ---- vertical 11-tap, 4-row register blocking, field-paired FMAs + SSIM ----
  {
    int col = tid & 31;
    int r0 = (tid >> 5) << 2;     // 0,4,...,28
    v2f aE[4] = {{0,0},{0,0},{0,0},{0,0}};
    v2f aQ[4] = {{0,0},{0,0},{0,0},{0,0}};
    float aP[4] = {0,0,0,0};
#pragma unroll
    for (int k = 0; k < 14; ++k) {
      v2f vE = htE[(r0+k)*STE + col];
      v2f vQ = htQ[(r0+k)*STE + col];
      float vP = htP[(r0+k)*STP + col];
#pragma unroll
      for (int j = 0; j < 4; ++j) {
        int t = k - j;
        if (t >= 0 && t < 11) {
          float w = G11[t];
          aE[j] += w * vE;
          aQ[j] += w * vQ;
          aP[j] = fmaf(w, vP, aP[j]);
        }
      }
    }
#pragma unroll
    for (int j = 0; j < 4; ++j) {
      float mu1 = aE[j].x, mu2 = aE[j].y;
      float x11 = aQ[j].x, x22 = aQ[j].y, x12 = aP[j];
      float mu1s = mu1*mu1, mu2s = mu2*mu2, mu12 = mu1*mu2;
      float num = (2.f*mu12 + C1F) * (2.f*(x12 - mu12) + C2F);
      float den = (mu1s + mu2s + C1F) * ((x11 - mu1s) + (x22 - mu2s) + C2F);
      ssim_sum += num * __builtin_amdgcn_rcpf(den);
    }
  }

#pragma unroll
  for (int off = 32; off > 0; off >>= 1) {
    abs_sum  += __shfl_down(abs_sum,  off);
    ssim_sum += __shfl_down(ssim_sum, off);
    h_sum    += __shfl_down(h_sum,    off);
    v_sum    += __shfl_down(v_sum,    off);
  }
  if ((tid & 63) == 0) {
    int w = tid >> 6;
    red[w*4+0]=abs_sum; red[w*4+1]=ssim_sum; red[w*4+2]=h_sum; red[w*4+3]=v_sum;
  }
  __syncthreads();
  if (tid < 4) {
    float s = red[tid] + red[4+tid] + red[8+tid] + red[12+tid];
    atomicAdd(&accum[tid], s);
  }
}

__device__ __forceinline__ void cos_hist_px(float mv, float g0, float g1, float g2,
                                            float P0, float P1, float P2,
                                            float& cos_sum, unsigned& cnt,
                                            unsigned* lh)
{
  // bin = floor(g*64) clipped (algebraically equals the reference index chain)
  int i0 = min(max((int)(g0*64.f), 0), 63);
  int i1 = min(max((int)(g1*64.f), 0), 63);
  int i2 = min(max((int)(g2*64.f), 0), 63);
  atomicAdd(&lh[i0],     1u);
  atomicAdd(&lh[64+i1],  1u);
  atomicAdd(&lh[128+i2], 1u);

  float p0 = P0*mv, p1 = P1*mv, p2 = P2*mv;
  float np2 = p0*p0 + p1*p1 + p2*p2;
  float invp = __builtin_amdgcn_rsqf(fmaxf(np2, 1e-24f));   // 1/max(||p||,1e-12)
  float t0 = (g0*mv*2.f - 1.f)*mv;
  float t1 = (g1*mv*2.f - 1.f)*mv;
  float t2 = (g2*mv*2.f - 1.f)*mv;
  float t2n = t0*t0 + t1*t1 + t2*t2;
  float invt = __builtin_amdgcn_rsqf(fmaxf(t2n, 1e-16f));   // 1/max(||t||,1e-8)
  float dot = p0*t0 + p1*t1 + p2*t2;
  // q = p*invp has ||q|| == 1 whenever p != 0 (n1==1); p==0 gives dot==0 -> cos=1
  cos_sum += 1.f - dot * invp * invt;
  cnt += (mv != 0.f) ? 1u : 0u;
}

__global__ __launch_bounds__(256)
void cos_hist_kernel(const float* __restrict__ pr, const float* __restrict__ gt,
                     const float* __restrict__ mk, float* __restrict__ accum,
                     unsigned* __restrict__ mcount, unsigned* __restrict__ hist)
{
  __shared__ unsigned lh[192];
  __shared__ float redf[4];
  __shared__ unsigned redi[4];
  int tid = threadIdx.x;
  for (int i = tid; i < 192; i += 256) lh[i] = 0u;
  __syncthreads();

  int b = blockIdx.x >> 3;
  int chunk = blockIdx.x & 7;
  const float4* pv = (const float4*)(pr + (size_t)b*3*HW);
  const float4* gv = (const float4*)(gt + (size_t)b*3*HW);
  const float4* mv4 = (const float4*)(mk + (size_t)b*HW);
  int base4 = chunk*2048;

  float cos_sum = 0.f;
  unsigned cnt = 0u;
  for (int it = 0; it < 8; ++it) {
    int i4 = base4 + it*256 + tid;
    float4 M  = mv4[i4];
    float4 G0 = gv[i4], G1 = gv[16384 + i4], G2 = gv[2*16384 + i4];
    float4 P0 = pv[i4], P1 = pv[16384 + i4], P2 = pv[2*16384 + i4];
    cos_hist_px(M.x, G0.x, G1.x, G2.x, P0.x, P1.x, P2.x, cos_sum, cnt, lh);
    cos_hist_px(M.y, G0.y, G1.y, G2.y, P0.y, P1.y, P2.y, cos_sum, cnt, lh);
    cos_hist_px(M.z, G0.z, G1.z, G2.z, P0.z, P1.z, P2.z, cos_sum, cnt, lh);
    cos_hist_px(M.w, G0.w, G1.w, G2.w, P0.w, P1.w, P2.w, cos_sum, cnt, lh);
  }

#pragma unroll
  for (int off = 32; off > 0; off >>= 1) {
    cos_sum += __shfl_down(cos_sum, off);
    cnt     += __shfl_down(cnt,     off);
  }
  if ((tid & 63) == 0) { redf[tid>>6] = cos_sum; redi[tid>>6] = cnt; }
  __syncthreads();
  if (tid == 0) {
    atomicAdd(&accum[4], redf[0]+redf[1]+redf[2]+redf[3]);
    atomicAdd(mcount, redi[0]+redi[1]+redi[2]+redi[3]);
  }
  for (int i = tid; i < 192; i += 256) {
    unsigned v = lh[i];
    if (v) atomicAdd(&hist[b*192 + i], v);
  }
}

__global__ __launch_bounds__(256)
void finalize_kernel(const float* __restrict__ nh, const unsigned* __restrict__ hist,
                     const float* __restrict__ accum, const unsigned* __restrict__ mcount,
                     float* __restrict__ out, int B)
{
  __shared__ float red[4];
  int tid = threadIdx.x;
  int n = B*192;
  float hs = 0.f;
  for (int i = tid; i < n; i += 256)
    hs += fabsf(nh[i] - (float)hist[i] * (1.f/65536.f));
#pragma unroll
  for (int off = 32; off > 0; off >>= 1) hs += __shfl_down(hs, off);
  if ((tid & 63) == 0) red[tid>>6] = hs;
  __syncthreads();
  if (tid == 0) {
    float hist_sum = red[0]+red[1]+red[2]+red[3];
    float Np = (float)B * 3.f * 65536.f;
    float L_dehaze = accum[0] / Np;
    float L_ssim = 1.f - accum[1] / Np;
    float L_tv = accum[2] / ((float)B*3.f*256.f*255.f)
               + accum[3] / ((float)B*3.f*255.f*256.f);
    float L_hist = hist_sum / (float)n;
    float M = (float)(*mcount);
    float back = (float)B * 65536.f - M;
    float L_normal = (accum[4] - back) / M;
    out[0] = 10.f*L_dehaze + L_ssim + L_tv + L_hist + 100.f*L_normal;
  }
}

extern "C" void kernel_launch(void* const* d_in, const int* in_sizes, int n_in,
                              void* d_out, int out_size, void* d_ws, size_t ws_size,
                              hipStream_t stream)
{
  const float* predict = (const float*)d_in[0];
  const float* gt      = (const float*)d_in[1];
  const float* dehaze  = (const float*)d_in[2];
  const float* cleanw  = (const float*)d_in[3];
  const float* nh      = (const float*)d_in[4];
  const float* mask    = (const float*)d_in[5];
  int B = in_sizes[0] / (3*HW);

  float* accum      = (float*)d_ws;
  unsigned* mcount  = (unsigned*)((char*)d_ws + 24);
  unsigned* hist    = (unsigned*)((char*)d_ws + 64);

  hipMemsetAsync(d_ws, 0, 64 + (size_t)B*192*4, stream);

  cos_hist_kernel<<<B*8, 256, 0, stream>>>(predict, gt, mask, accum, mcount, hist);
  ssim_tv_kernel<<<B*3*64, 256, 0, stream>>>(dehaze, cleanw, mask, accum);
  finalize_kernel<<<1, 256, 0, stream>>>(nh, hist, accum, mcount, (float*)d_out, B);
}